// Round 12
// baseline (400.824 us; speedup 1.0000x reference)
//
#include <hip/hip_runtime.h>
#include <float.h>

// Tropical (max-plus) linear: y[b,o] = max_i (x[b,i] + W[o,i])
// B=512, I=1024, O=1024, fp32 in/out. No MFMA (max-plus) -> VALU.
//
// Round-12: FP16 internal compute (tolerance 0.1625 >> fp16 error ~0.006).
//  * Convert+transpose x->xh[I][B], W->wh[I][O] as _Float16.
//  * Main: r8 structure (128x128 tile, 256 thr, KSPLIT=16, KT=16, NCH=4,
//    double-buffered global_load_lds), but LDS tiles are half-width:
//    4 ds_read_b128 per k-pair (was 8) and packed v_pk_add_f16/v_pk_max_f16:
//    1.0 VALU instr/MAC (was 1.5). Floors: LDS 5.1 us, VALU 6.8 us.
//  * Register-state rule (r5/r7/r9 demotions): NO 64/128-bit vector-typed
//    storage. acc = scalar `unsigned` array (each = packed half2), bit-cast
//    per op; half2v/float4/uint4 only as NAMED temps. Packed-f16 ops use
//    single VGPRs (no even-pair alignment -> no allocator fragmentation).
//  * Slabs fp16 (1 MB each) -> reduce reads 16 MB, converts to fp32 y.

#define B_DIM 512
#define I_DIM 1024
#define O_DIM 1024
#define BT 128
#define OT 128
#define KT 16            // k per staged chunk; tile = KT*128 halves = 4 KB

typedef _Float16 half2v __attribute__((ext_vector_type(2)));

__device__ __forceinline__ void g2lds16(const void* g, void* l) {
    __builtin_amdgcn_global_load_lds(
        (const __attribute__((address_space(1))) void*)g,
        (__attribute__((address_space(3))) void*)l, 16, 0, 0);
}

// one packed o-pair update: acc = max(acc, max(w_k + x_k, w_k1 + x_k1))
#define TROP_PAIR(II, PP, WK, WK1) do {                                    \
    half2v s0 = (WK) + xlo;                                                \
    half2v s1 = (WK1) + ylo;                                               \
    s0 = __builtin_elementwise_max(s0, s1);                                \
    half2v a = __builtin_bit_cast(half2v, acc_u[II][PP]);                  \
    a = __builtin_elementwise_max(a, s0);                                  \
    acc_u[II][PP] = __builtin_bit_cast(unsigned, a);                       \
} while (0)

#define TROP_ROW(II, XL, YL) do {                                          \
    const _Float16 xlo = (XL);                                             \
    const _Float16 ylo = (YL);                                             \
    TROP_PAIR(II, 0, w00, w10);                                            \
    TROP_PAIR(II, 1, w01, w11);                                            \
    TROP_PAIR(II, 2, w02, w12);                                            \
    TROP_PAIR(II, 3, w03, w13);                                            \
} while (0)

template <int KB>   // k handled per block
__global__ __launch_bounds__(256, 2) void trop_main(
    const _Float16* __restrict__ xh,   // [I_DIM][B_DIM]
    const _Float16* __restrict__ wh,   // [I_DIM][O_DIM]
    _Float16* __restrict__ part)       // [KSPLIT][B_DIM][O_DIM]
{
    constexpr int NCH = KB / KT;
    static_assert(KB % KT == 0, "");
    __shared__ __align__(16) char xs[2][KT * BT * 2];   // [k][b] halves, 4 KB
    __shared__ __align__(16) char ws[2][KT * OT * 2];   // [k][o] halves, 4 KB

    const int tid  = threadIdx.x;
    const int to   = tid & 15;      // o-octet selector (8 contiguous o)
    const int tb   = tid >> 4;      // b-octet selector (8 contiguous b)
    const int wave = tid >> 6;      // 0..3
    const int lane = tid & 63;
    const int o0 = blockIdx.x * OT;
    const int b0 = blockIdx.y * BT;
    const int kz = blockIdx.z;
    const int kbase = kz * KB;

    const int rk4 = lane >> 4;          // k-subrow within one 1KB DMA (4 rows)
    const int cl  = (lane & 15) * 16;   // byte col within 256B row

    // acc[i][p]: b = b0+8*tb+i, o-pair = o0+8*to+{2p,2p+1}; packed half2
    unsigned acc_u[8][4];
    #pragma unroll
    for (int i = 0; i < 8; ++i)
        #pragma unroll
        for (int p = 0; p < 4; ++p)
            acc_u[i][p] = 0xFBFFFBFFu;   // half2(-65504, -65504)

    // chunk = 16 k-rows x 128 halves (256B/row): 4 x-DMAs + 4 w-DMAs, 1+1/wave
    auto stage = [&](int c, int buf) {
        const int k0 = kbase + c * KT;
        const int t = wave;             // wave-uniform LDS base
        g2lds16((const char*)xh + (size_t)(k0 + 4 * t + rk4) * (B_DIM * 2)
                    + b0 * 2 + cl,
                &xs[buf][t * 1024]);
        g2lds16((const char*)wh + (size_t)(k0 + 4 * t + rk4) * (O_DIM * 2)
                    + o0 * 2 + cl,
                &ws[buf][t * 1024]);
    };

    auto compute = [&](int buf) {
        const char* xB = &xs[buf][16 * tb];   // all reads: static imm offsets
        const char* wB = &ws[buf][16 * to];
        #pragma unroll                         // FULL unroll: 8 k-pairs
        for (int k = 0; k < KT; k += 2) {
            const float4 xr0 = *(const float4*)(xB + k * 256);
            const float4 xr1 = *(const float4*)(xB + (k + 1) * 256);
            const float4 wr0 = *(const float4*)(wB + k * 256);
            const float4 wr1 = *(const float4*)(wB + (k + 1) * 256);

            const half2v xk0 = __builtin_bit_cast(half2v, xr0.x);
            const half2v xk1 = __builtin_bit_cast(half2v, xr0.y);
            const half2v xk2 = __builtin_bit_cast(half2v, xr0.z);
            const half2v xk3 = __builtin_bit_cast(half2v, xr0.w);
            const half2v yk0 = __builtin_bit_cast(half2v, xr1.x);
            const half2v yk1 = __builtin_bit_cast(half2v, xr1.y);
            const half2v yk2 = __builtin_bit_cast(half2v, xr1.z);
            const half2v yk3 = __builtin_bit_cast(half2v, xr1.w);
            const half2v w00 = __builtin_bit_cast(half2v, wr0.x);
            const half2v w01 = __builtin_bit_cast(half2v, wr0.y);
            const half2v w02 = __builtin_bit_cast(half2v, wr0.z);
            const half2v w03 = __builtin_bit_cast(half2v, wr0.w);
            const half2v w10 = __builtin_bit_cast(half2v, wr1.x);
            const half2v w11 = __builtin_bit_cast(half2v, wr1.y);
            const half2v w12 = __builtin_bit_cast(half2v, wr1.z);
            const half2v w13 = __builtin_bit_cast(half2v, wr1.w);

            TROP_ROW(0, xk0.x, yk0.x);
            TROP_ROW(1, xk0.y, yk0.y);
            TROP_ROW(2, xk1.x, yk1.x);
            TROP_ROW(3, xk1.y, yk1.y);
            TROP_ROW(4, xk2.x, yk2.x);
            TROP_ROW(5, xk2.y, yk2.y);
            TROP_ROW(6, xk3.x, yk3.x);
            TROP_ROW(7, xk3.y, yk3.y);
        }
    };

    stage(0, 0);
    #pragma unroll
    for (int c = 0; c < NCH; ++c) {
        __syncthreads();                              // chunk c staged; prev reads done
        if (c + 1 < NCH) stage(c + 1, (c + 1) & 1);   // DMA overlaps compute
        compute(c & 1);
    }

    // epilogue: packed-half uint4 stores (16 lanes -> 256B contiguous)
    _Float16* pout = part + (size_t)kz * (B_DIM * O_DIM);
    #pragma unroll
    for (int i = 0; i < 8; ++i) {
        const int b = b0 + 8 * tb + i;
        uint4 v = make_uint4(acc_u[i][0], acc_u[i][1], acc_u[i][2], acc_u[i][3]);
        *(uint4*)((char*)pout + ((size_t)b * O_DIM + o0 + 8 * to) * 2) = v;
    }
}

// ---- fused convert+transpose: fp32 in -> _Float16 out, transposed
// z=0: x (512x1024) -> xh[1024][512]; z=1,2: W halves -> wh[1024][1024]
__global__ __launch_bounds__(256) void transpose3h(
    const float* __restrict__ x, _Float16* __restrict__ xh,
    const float* __restrict__ W, _Float16* __restrict__ wh)
{
    __shared__ float tile[32][33];
    const int tx = threadIdx.x;   // 0..31
    const int ty = threadIdx.y;   // 0..7
    const int z  = blockIdx.z;
    const float* in; _Float16* out; int dst_ld;
    if (z == 0) { in = x;                       out = xh;        dst_ld = B_DIM; }
    else        { in = W + (size_t)(z - 1) * 512 * I_DIM;
                  out = wh + (z - 1) * 512;                      dst_ld = O_DIM; }
    const int r0 = blockIdx.y * 32;
    const int c0 = blockIdx.x * 32;
    #pragma unroll
    for (int i = 0; i < 4; ++i)
        tile[ty + 8 * i][tx] = in[(size_t)(r0 + ty + 8 * i) * I_DIM + c0 + tx];
    __syncthreads();
    #pragma unroll
    for (int i = 0; i < 4; ++i)
        out[(size_t)(c0 + ty + 8 * i) * dst_ld + r0 + tx] =
            (_Float16)tile[tx][ty + 8 * i];
}

template <int KS>
__global__ __launch_bounds__(256) void trop_reduce_h(
    const uint4* __restrict__ part, float* __restrict__ y)
{
    constexpr int STRIDE = B_DIM * O_DIM / 8;   // uint4s per slab
    const int idx = blockIdx.x * 256 + threadIdx.x;
    uint4 m = part[idx];
    #pragma unroll
    for (int s = 1; s < KS; ++s) {
        const uint4 v = part[(size_t)s * STRIDE + idx];
        half2v a, b;
        a = __builtin_bit_cast(half2v, m.x); b = __builtin_bit_cast(half2v, v.x);
        m.x = __builtin_bit_cast(unsigned, __builtin_elementwise_max(a, b));
        a = __builtin_bit_cast(half2v, m.y); b = __builtin_bit_cast(half2v, v.y);
        m.y = __builtin_bit_cast(unsigned, __builtin_elementwise_max(a, b));
        a = __builtin_bit_cast(half2v, m.z); b = __builtin_bit_cast(half2v, v.z);
        m.z = __builtin_bit_cast(unsigned, __builtin_elementwise_max(a, b));
        a = __builtin_bit_cast(half2v, m.w); b = __builtin_bit_cast(half2v, v.w);
        m.w = __builtin_bit_cast(unsigned, __builtin_elementwise_max(a, b));
    }
    const half2v h0 = __builtin_bit_cast(half2v, m.x);
    const half2v h1 = __builtin_bit_cast(half2v, m.y);
    const half2v h2 = __builtin_bit_cast(half2v, m.z);
    const half2v h3 = __builtin_bit_cast(half2v, m.w);
    float4 o0 = make_float4((float)h0.x, (float)h0.y, (float)h1.x, (float)h1.y);
    float4 o1 = make_float4((float)h2.x, (float)h2.y, (float)h3.x, (float)h3.y);
    ((float4*)y)[2 * idx]     = o0;
    ((float4*)y)[2 * idx + 1] = o1;
}

// correctness-net fallback if d_ws is tiny (fp32, exact)
__global__ __launch_bounds__(256) void trop_naive(
    const float* __restrict__ x, const float* __restrict__ W,
    float* __restrict__ y)
{
    const int idx = blockIdx.x * 256 + threadIdx.x;
    const int b = idx / O_DIM, o = idx % O_DIM;
    float m = -FLT_MAX;
    for (int i = 0; i < I_DIM; ++i)
        m = fmaxf(m, x[b * I_DIM + i] + W[o * I_DIM + i]);
    y[idx] = m;
}

extern "C" void kernel_launch(void* const* d_in, const int* in_sizes, int n_in,
                              void* d_out, int out_size, void* d_ws, size_t ws_size,
                              hipStream_t stream) {
    const float* x = (const float*)d_in[0];
    const float* W = (const float*)d_in[1];
    float* y = (float*)d_out;

    const size_t slab_h = (size_t)B_DIM * O_DIM * 2;              // 1 MB
    const size_t xh_sz  = (size_t)B_DIM * I_DIM * 2;              // 1 MB
    const size_t wh_sz  = (size_t)O_DIM * I_DIM * 2;              // 2 MB
    const dim3 rgrid(B_DIM * O_DIM / 8 / 256);                    // 256 blocks
    const dim3 tgrid(I_DIM / 32, 512 / 32, 3);
    const dim3 tblk(32, 8);

    auto launch = [&](int ksplit, auto kmain, auto kreduce) {
        _Float16* part = (_Float16*)d_ws;
        _Float16* xh = part + (size_t)ksplit * (B_DIM * O_DIM);
        _Float16* wh = xh + (size_t)B_DIM * I_DIM;
        transpose3h<<<tgrid, tblk, 0, stream>>>(x, xh, W, wh);
        kmain(dim3(O_DIM / OT, B_DIM / BT, ksplit), xh, wh, part);
        kreduce((const uint4*)part);
    };

    if (ws_size >= 16 * slab_h + xh_sz + wh_sz) {        // 19 MB
        launch(16,
            [&](dim3 g, const _Float16* a, const _Float16* b, _Float16* p) {
                trop_main<I_DIM / 16><<<g, 256, 0, stream>>>(a, b, p); },
            [&](const uint4* p) {
                trop_reduce_h<16><<<rgrid, 256, 0, stream>>>(p, y); });
    } else if (ws_size >= 8 * slab_h + xh_sz + wh_sz) {  // 11 MB
        launch(8,
            [&](dim3 g, const _Float16* a, const _Float16* b, _Float16* p) {
                trop_main<I_DIM / 8><<<g, 256, 0, stream>>>(a, b, p); },
            [&](const uint4* p) {
                trop_reduce_h<8><<<rgrid, 256, 0, stream>>>(p, y); });
    } else if (ws_size >= slab_h + xh_sz + wh_sz) {      // 4 MB
        launch(1,
            [&](dim3 g, const _Float16* a, const _Float16* b, _Float16* p) {
                trop_main<I_DIM><<<g, 256, 0, stream>>>(a, b, p); },
            [&](const uint4* p) {
                trop_reduce_h<1><<<rgrid, 256, 0, stream>>>(p, y); });
    } else {
        trop_naive<<<dim3(B_DIM * O_DIM / 256), 256, 0, stream>>>(x, W, y);
    }
}

// Round 13
// 104.531 us; speedup vs baseline: 3.8345x; 3.8345x over previous
//
#include <hip/hip_runtime.h>
#include <float.h>

// Tropical (max-plus) linear: y[b,o] = max_i (x[b,i] + W[o,i])
// B=512, I=1024, O=1024, fp32 in/out. No MFMA (max-plus) -> fp32 VALU.
//
// Round-13: fp16 in LDS, SCALAR f32 compute.
//  FINAL CODEGEN RULE (5 demotion detonations: r5 f32x4, r7 f32x2 arrays,
//  r9 named f32x2, r12 half2v): ANY ext_vector arithmetic in the hot loop
//  -> allocator demotes register state to scratch (~1 GB HBM traffic, ~8x).
//  Only pure scalar-float dataflow compiles clean. This kernel: uint4 load
//  temps -> unsigned scalars -> v_cvt_f32_f16 -> r8's verbatim scalar body.
//  Why fp16 LDS: corrected accounting shows r8 was LDS-issue-bound
//  (8 ds_read_b128/thread/k-pair = 20.5 us floor vs VALU 10.2). fp16 tiles
//  halve that: 4 b128/k-pair (LDS 10.2) + 32 cvt (VALU 11.9). Serial 22 vs 31.
//  Accuracy: r12 measured absmax 0.031 << 0.1625 tolerance (fp16 ok).
//  Everything else r8-proven: 128x128 tile, 256 thr, KSPLIT=16, KT=16 NCH=4,
//  double-buffered global_load_lds, f32 slabs + reduce, fused transpose+cvt.

#define B_DIM 512
#define I_DIM 1024
#define O_DIM 1024
#define BT 128
#define OT 128
#define KT 16            // k per staged chunk; fp16 tile = 16x128 halves = 4 KB

__device__ __forceinline__ void g2lds16(const void* g, void* l) {
    __builtin_amdgcn_global_load_lds(
        (const __attribute__((address_space(1))) void*)g,
        (__attribute__((address_space(3))) void*)l, 16, 0, 0);
}

// scalar fp16 -> fp32 unpack (v_cvt_f32_f16, op_sel/lshr for high half)
__device__ __forceinline__ float lo16f(unsigned u) {
    return (float)__builtin_bit_cast(_Float16, (unsigned short)(u & 0xffffu));
}
__device__ __forceinline__ float hi16f(unsigned u) {
    return (float)__builtin_bit_cast(_Float16, (unsigned short)(u >> 16));
}

template <int KB>   // k handled per block
__global__ __launch_bounds__(256, 2) void trop_main(
    const _Float16* __restrict__ xh,   // [I_DIM][B_DIM]
    const _Float16* __restrict__ wh,   // [I_DIM][O_DIM]
    float* __restrict__ part)          // [KSPLIT][B_DIM][O_DIM] (or y if z==1)
{
    constexpr int NCH = KB / KT;
    static_assert(KB % KT == 0, "");
    __shared__ __align__(16) char xs[2][KT * BT * 2];   // [k][b] halves, 4 KB
    __shared__ __align__(16) char ws[2][KT * OT * 2];   // [k][o] halves, 4 KB

    const int tid  = threadIdx.x;
    const int to   = tid & 15;      // o-octet selector (8 contiguous o)
    const int tb   = tid >> 4;      // b-octet selector (8 contiguous b)
    const int wave = tid >> 6;      // 0..3
    const int lane = tid & 63;
    const int o0 = blockIdx.x * OT;
    const int b0 = blockIdx.y * BT;
    const int kz = blockIdx.z;
    const int kbase = kz * KB;

    const int rk4 = lane >> 4;          // k-subrow within one 1KB DMA (4 rows)
    const int cl  = (lane & 15) * 16;   // byte col within 256B tile row

    float acc[8][8];                    // SCALAR regs — the only clean form
    #pragma unroll
    for (int i = 0; i < 8; ++i)
        #pragma unroll
        for (int j = 0; j < 8; ++j)
            acc[i][j] = -FLT_MAX;

    // chunk = 16 k-rows x 256 B: 4 x-DMAs + 4 w-DMAs, 1+1 per wave
    auto stage = [&](int c, int buf) {
        const int k0 = kbase + c * KT;
        const int t = wave;             // wave-uniform LDS base
        g2lds16((const char*)xh + (size_t)(k0 + 4 * t + rk4) * (B_DIM * 2)
                    + b0 * 2 + cl,
                &xs[buf][t * 1024]);
        g2lds16((const char*)wh + (size_t)(k0 + 4 * t + rk4) * (O_DIM * 2)
                    + o0 * 2 + cl,
                &ws[buf][t * 1024]);
    };

    auto compute = [&](int buf) {
        const char* xB = &xs[buf][16 * tb];   // static imm offsets from base
        const char* wB = &ws[buf][16 * to];
        #pragma unroll                         // FULL unroll: 8 k-pairs
        for (int k = 0; k < KT; k += 2) {
            const uint4 xu0 = *(const uint4*)(xB + k * 256);        // 8 halves
            const uint4 xu1 = *(const uint4*)(xB + (k + 1) * 256);
            const uint4 wu0 = *(const uint4*)(wB + k * 256);
            const uint4 wu1 = *(const uint4*)(wB + (k + 1) * 256);

            const float xa[8] = {lo16f(xu0.x), hi16f(xu0.x), lo16f(xu0.y), hi16f(xu0.y),
                                 lo16f(xu0.z), hi16f(xu0.z), lo16f(xu0.w), hi16f(xu0.w)};
            const float xb[8] = {lo16f(xu1.x), hi16f(xu1.x), lo16f(xu1.y), hi16f(xu1.y),
                                 lo16f(xu1.z), hi16f(xu1.z), lo16f(xu1.w), hi16f(xu1.w)};
            const float wa[8] = {lo16f(wu0.x), hi16f(wu0.x), lo16f(wu0.y), hi16f(wu0.y),
                                 lo16f(wu0.z), hi16f(wu0.z), lo16f(wu0.w), hi16f(wu0.w)};
            const float wb[8] = {lo16f(wu1.x), hi16f(wu1.x), lo16f(wu1.y), hi16f(wu1.y),
                                 lo16f(wu1.z), hi16f(wu1.z), lo16f(wu1.w), hi16f(wu1.w)};

            #pragma unroll
            for (int i = 0; i < 8; ++i)
                #pragma unroll
                for (int j = 0; j < 8; ++j) {
                    const float s0 = xa[i] + wa[j];
                    const float s1 = xb[i] + wb[j];
                    acc[i][j] = fmaxf(acc[i][j], fmaxf(s0, s1));   // v_max3_f32
                }
        }
    };

    stage(0, 0);
    #pragma unroll
    for (int c = 0; c < NCH; ++c) {
        __syncthreads();                              // chunk c staged; prev reads done
        if (c + 1 < NCH) stage(c + 1, (c + 1) & 1);   // DMA overlaps compute
        compute(c & 1);
    }

    // epilogue: f32 slab, 2 float4 stores per row (o-octet contiguous)
    float* pout = part + (size_t)kz * (B_DIM * O_DIM);
    #pragma unroll
    for (int i = 0; i < 8; ++i) {
        const int b = b0 + 8 * tb + i;
        float4 v0 = make_float4(acc[i][0], acc[i][1], acc[i][2], acc[i][3]);
        float4 v1 = make_float4(acc[i][4], acc[i][5], acc[i][6], acc[i][7]);
        *(float4*)&pout[(size_t)b * O_DIM + o0 + 8 * to]     = v0;
        *(float4*)&pout[(size_t)b * O_DIM + o0 + 8 * to + 4] = v1;
    }
}

// ---- fused convert+transpose: fp32 in -> _Float16 out, transposed
// z=0: x (512x1024) -> xh[1024][512]; z=1,2: W halves -> wh[1024][1024]
// (r12-verified correct: absmax 0.031 passed)
__global__ __launch_bounds__(256) void transpose3h(
    const float* __restrict__ x, _Float16* __restrict__ xh,
    const float* __restrict__ W, _Float16* __restrict__ wh)
{
    __shared__ float tile[32][33];
    const int tx = threadIdx.x;   // 0..31
    const int ty = threadIdx.y;   // 0..7
    const int z  = blockIdx.z;
    const float* in; _Float16* out; int dst_ld;
    if (z == 0) { in = x;                       out = xh;        dst_ld = B_DIM; }
    else        { in = W + (size_t)(z - 1) * 512 * I_DIM;
                  out = wh + (z - 1) * 512;                      dst_ld = O_DIM; }
    const int r0 = blockIdx.y * 32;
    const int c0 = blockIdx.x * 32;
    #pragma unroll
    for (int i = 0; i < 4; ++i)
        tile[ty + 8 * i][tx] = in[(size_t)(r0 + ty + 8 * i) * I_DIM + c0 + tx];
    __syncthreads();
    #pragma unroll
    for (int i = 0; i < 4; ++i)
        out[(size_t)(c0 + ty + 8 * i) * dst_ld + r0 + tx] =
            (_Float16)tile[tx][ty + 8 * i];
}

template <int KS>
__global__ __launch_bounds__(256) void trop_reduce(
    const float* __restrict__ part, float* __restrict__ y)
{
    constexpr int N4 = B_DIM * O_DIM / 4;
    const int idx = blockIdx.x * 256 + threadIdx.x;
    const float4* p = (const float4*)part;
    float4 m = p[idx];
    #pragma unroll
    for (int s = 1; s < KS; ++s) {
        const float4 v = p[(size_t)s * N4 + idx];
        m.x = fmaxf(m.x, v.x); m.y = fmaxf(m.y, v.y);
        m.z = fmaxf(m.z, v.z); m.w = fmaxf(m.w, v.w);
    }
    ((float4*)y)[idx] = m;
}

// correctness-net fallback if d_ws is tiny (fp32, exact)
__global__ __launch_bounds__(256) void trop_naive(
    const float* __restrict__ x, const float* __restrict__ W,
    float* __restrict__ y)
{
    const int idx = blockIdx.x * 256 + threadIdx.x;
    const int b = idx / O_DIM, o = idx % O_DIM;
    float m = -FLT_MAX;
    for (int i = 0; i < I_DIM; ++i)
        m = fmaxf(m, x[b * I_DIM + i] + W[o * I_DIM + i]);
    y[idx] = m;
}

extern "C" void kernel_launch(void* const* d_in, const int* in_sizes, int n_in,
                              void* d_out, int out_size, void* d_ws, size_t ws_size,
                              hipStream_t stream) {
    const float* x = (const float*)d_in[0];
    const float* W = (const float*)d_in[1];
    float* y = (float*)d_out;

    const size_t slab  = (size_t)B_DIM * O_DIM * sizeof(float);   // 2 MB
    const size_t xh_sz = (size_t)B_DIM * I_DIM * 2;               // 1 MB
    const size_t wh_sz = (size_t)O_DIM * I_DIM * 2;               // 2 MB
    const dim3 rgrid(B_DIM * O_DIM / 4 / 256);
    const dim3 tgrid(I_DIM / 32, 512 / 32, 3);
    const dim3 tblk(32, 8);

    auto prep = [&](int ksplit) -> _Float16* {   // returns xh; wh follows
        _Float16* xh = (_Float16*)((char*)d_ws + (size_t)ksplit * slab);
        _Float16* wh = xh + (size_t)B_DIM * I_DIM;
        transpose3h<<<tgrid, tblk, 0, stream>>>(x, xh, W, wh);
        return xh;
    };

    if (ws_size >= 16 * slab + xh_sz + wh_sz) {          // 35 MB
        float* part = (float*)d_ws;
        _Float16* xh = prep(16);
        _Float16* wh = xh + (size_t)B_DIM * I_DIM;
        trop_main<I_DIM / 16><<<dim3(O_DIM / OT, B_DIM / BT, 16), 256, 0, stream>>>(xh, wh, part);
        trop_reduce<16><<<rgrid, 256, 0, stream>>>(part, y);
    } else if (ws_size >= 8 * slab + xh_sz + wh_sz) {    // 19 MB
        float* part = (float*)d_ws;
        _Float16* xh = prep(8);
        _Float16* wh = xh + (size_t)B_DIM * I_DIM;
        trop_main<I_DIM / 8><<<dim3(O_DIM / OT, B_DIM / BT, 8), 256, 0, stream>>>(xh, wh, part);
        trop_reduce<8><<<rgrid, 256, 0, stream>>>(part, y);
    } else if (ws_size >= xh_sz + wh_sz) {               // 3 MB: no K-split
        _Float16* xh = prep(0);
        _Float16* wh = xh + (size_t)B_DIM * I_DIM;
        trop_main<I_DIM><<<dim3(O_DIM / OT, B_DIM / BT, 1), 256, 0, stream>>>(xh, wh, y);
    } else {
        trop_naive<<<dim3(B_DIM * O_DIM / 256), 256, 0, stream>>>(x, W, y);
    }
}

// Round 14
// 88.783 us; speedup vs baseline: 4.5146x; 1.1774x over previous
//
#include <hip/hip_runtime.h>
#include <float.h>

// Tropical (max-plus) linear: y[b,o] = max_i (x[b,i] + W[o,i])
// B=512, I=1024, O=1024, fp32. No MFMA (max-plus) -> fp32 VALU.
//
// Round-14: BARRIER-FREE K-loop via wave-private LDS tiles.
//  Why: r8/r11's ~30 us main is 1.45x the 20.4 us serial instruction floor
//  (LDS 10.2 + VALU 10.2); the gap is the per-chunk vmcnt(0)+s_barrier
//  lockstep where all 4 waves stall together. Here each wave stages its OWN
//  x-slice (1 KB) + w-tile (4 KB) per KT=8 chunk into wave-private
//  double-buffered LDS -> zero __syncthreads in the whole kernel; waves
//  free-run and cover each other's DMA waits. w is DMA-duplicated 4x/block
//  (L2/L3-served; HBM FETCH unchanged). Chunk loop fully unrolled so buf is
//  compile-time -> waitcnt pass can prove buffer disjointness (precise
//  vmcnt, prefetch stays in flight).
//  CODEGEN RULE (5 demotions: r5/r7/r9/r12): pure scalar-float dataflow only;
//  float4 solely as an immediate LDS-load temp. r8's body verbatim.
//  LDS: (1+4 KB) x 2 bufs x 4 waves = 40 KB/block, 2 blocks/CU = 80 <= 160.

#define B_DIM 512
#define I_DIM 1024
#define O_DIM 1024
#define BT 128           // block b-tile (32 per wave)
#define OT 128           // block o-tile (full, per wave)
#define KT 8             // k per staged chunk

__device__ __forceinline__ void g2lds16(const float* g, float* l) {
    __builtin_amdgcn_global_load_lds(
        (const __attribute__((address_space(1))) void*)g,
        (__attribute__((address_space(3))) void*)l, 16, 0, 0);
}

template <int KB>   // k handled per block
__global__ __launch_bounds__(256, 2) void trop_main(
    const float* __restrict__ xT,   // [I_DIM][B_DIM]
    const float* __restrict__ wT,   // [I_DIM][O_DIM]
    float* __restrict__ part)       // [KSPLIT][B_DIM][O_DIM] (or y if z==1)
{
    constexpr int NCH = KB / KT;
    static_assert(KB % KT == 0, "");
    __shared__ __align__(16) float xs[4][2][KT * 32];    // [wave][buf][k][b32]
    __shared__ __align__(16) float ws[4][2][KT * 128];   // [wave][buf][k][o]

    const int tid  = threadIdx.x;
    const int wave = tid >> 6;          // 0..3: owns b-rows [32*wave, 32*wave+32)
    const int lane = tid & 63;
    const int to   = lane & 15;         // o-quad selector (0..15)
    const int tbw  = lane >> 4;         // b-quad selector within wave (0..3)
    const int o0 = blockIdx.x * OT;
    const int b0 = blockIdx.y * BT;
    const int bw0 = b0 + 32 * wave;     // wave's b-slice base
    const int kz = blockIdx.z;
    const int kbase = kz * KB;

    // stage lane geometry
    const int rk8 = lane >> 3;          // x DMA: k-row 0..7
    const int xc4 = (lane & 7) * 4;     //        b-col (floats)
    const int rk2 = lane >> 5;          // w DMA: k-subrow 0..1
    const int wc4 = (lane & 31) * 4;    //        o-col (floats)

    float acc[8][8];                    // SCALAR regs — the only clean form
    #pragma unroll
    for (int i = 0; i < 8; ++i)
        #pragma unroll
        for (int j = 0; j < 8; ++j)
            acc[i][j] = -FLT_MAX;

    // per-wave stage: 1 x-DMA (8 rows x 32 floats) + 4 w-DMAs (2 rows x 128)
    auto stage = [&](int c, int buf) {
        const int k0 = kbase + c * KT;
        g2lds16(&xT[(size_t)(k0 + rk8) * B_DIM + bw0 + xc4],
                &xs[wave][buf][0]);
        #pragma unroll
        for (int t = 0; t < 4; ++t)
            g2lds16(&wT[(size_t)(k0 + 2 * t + rk2) * O_DIM + o0 + wc4],
                    &ws[wave][buf][t * 256]);
    };

    auto compute = [&](int buf) {
        const float* xB = &xs[wave][buf][4 * tbw];   // static imm offsets
        const float* wB = &ws[wave][buf][4 * to];
        #pragma unroll                                // 4 k-pairs
        for (int k = 0; k < KT; k += 2) {
            const float4 xa0 = *(const float4*)&xB[k * 32];
            const float4 xa1 = *(const float4*)&xB[k * 32 + 16];
            const float4 xb0 = *(const float4*)&xB[(k + 1) * 32];
            const float4 xb1 = *(const float4*)&xB[(k + 1) * 32 + 16];
            const float4 wa0 = *(const float4*)&wB[k * 128];
            const float4 wa1 = *(const float4*)&wB[k * 128 + 64];
            const float4 wb0 = *(const float4*)&wB[(k + 1) * 128];
            const float4 wb1 = *(const float4*)&wB[(k + 1) * 128 + 64];

            const float xa[8] = {xa0.x, xa0.y, xa0.z, xa0.w, xa1.x, xa1.y, xa1.z, xa1.w};
            const float xb[8] = {xb0.x, xb0.y, xb0.z, xb0.w, xb1.x, xb1.y, xb1.z, xb1.w};
            const float wa[8] = {wa0.x, wa0.y, wa0.z, wa0.w, wa1.x, wa1.y, wa1.z, wa1.w};
            const float wb[8] = {wb0.x, wb0.y, wb0.z, wb0.w, wb1.x, wb1.y, wb1.z, wb1.w};

            #pragma unroll
            for (int i = 0; i < 8; ++i)
                #pragma unroll
                for (int j = 0; j < 8; ++j) {
                    const float s0 = xa[i] + wa[j];
                    const float s1 = xb[i] + wb[j];
                    acc[i][j] = fmaxf(acc[i][j], fmaxf(s0, s1));   // v_max3_f32
                }
        }
    };

    // barrier-free pipeline: wave-private buffers, compiler-inserted vmcnt only
    stage(0, 0);
    #pragma unroll
    for (int c = 0; c < NCH; ++c) {
        if (c + 1 < NCH) stage(c + 1, (c + 1) & 1);
        compute(c & 1);
    }

    // epilogue: coalesced float4 stores into private slab
    float* pout = part + (size_t)kz * (B_DIM * O_DIM);
    #pragma unroll
    for (int i = 0; i < 8; ++i) {
        const int b = bw0 + (i >> 2) * 16 + 4 * tbw + (i & 3);
        float4 v0 = make_float4(acc[i][0], acc[i][1], acc[i][2], acc[i][3]);
        float4 v1 = make_float4(acc[i][4], acc[i][5], acc[i][6], acc[i][7]);
        *(float4*)&pout[(size_t)b * O_DIM + o0 + 4 * to]      = v0;
        *(float4*)&pout[(size_t)b * O_DIM + o0 + 64 + 4 * to] = v1;
    }
}

// ---- fused transpose: z=0 -> xT from x (512x1024); z=1,2 -> wT halves
__global__ __launch_bounds__(256) void transpose3(
    const float* __restrict__ x, float* __restrict__ xT,
    const float* __restrict__ W, float* __restrict__ wT)
{
    __shared__ float tile[32][33];
    const int tx = threadIdx.x;   // 0..31
    const int ty = threadIdx.y;   // 0..7
    const int z  = blockIdx.z;
    const float* in; float* out; int dst_ld;
    if (z == 0) { in = x;                  out = xT;            dst_ld = B_DIM; }
    else        { in = W + (size_t)(z - 1) * 512 * I_DIM;
                  out = wT + (z - 1) * 512;                     dst_ld = O_DIM; }
    const int r0 = blockIdx.y * 32;
    const int c0 = blockIdx.x * 32;
    #pragma unroll
    for (int i = 0; i < 4; ++i)
        tile[ty + 8 * i][tx] = in[(size_t)(r0 + ty + 8 * i) * I_DIM + c0 + tx];
    __syncthreads();
    #pragma unroll
    for (int i = 0; i < 4; ++i)
        out[(size_t)(c0 + ty + 8 * i) * dst_ld + r0 + tx] = tile[tx][ty + 8 * i];
}

template <int KS>
__global__ __launch_bounds__(256) void trop_reduce(
    const float* __restrict__ part, float* __restrict__ y)
{
    constexpr int N4 = B_DIM * O_DIM / 4;
    const int idx = blockIdx.x * 256 + threadIdx.x;
    const float4* p = (const float4*)part;
    float4 m = p[idx];
    #pragma unroll
    for (int s = 1; s < KS; ++s) {
        const float4 v = p[(size_t)s * N4 + idx];
        m.x = fmaxf(m.x, v.x); m.y = fmaxf(m.y, v.y);
        m.z = fmaxf(m.z, v.z); m.w = fmaxf(m.w, v.w);
    }
    ((float4*)y)[idx] = m;
}

// correctness-net fallback if d_ws is tiny
__global__ __launch_bounds__(256) void trop_naive(
    const float* __restrict__ x, const float* __restrict__ W,
    float* __restrict__ y)
{
    const int idx = blockIdx.x * 256 + threadIdx.x;
    const int b = idx / O_DIM, o = idx % O_DIM;
    float m = -FLT_MAX;
    for (int i = 0; i < I_DIM; ++i)
        m = fmaxf(m, x[b * I_DIM + i] + W[o * I_DIM + i]);
    y[idx] = m;
}

extern "C" void kernel_launch(void* const* d_in, const int* in_sizes, int n_in,
                              void* d_out, int out_size, void* d_ws, size_t ws_size,
                              hipStream_t stream) {
    const float* x = (const float*)d_in[0];
    const float* W = (const float*)d_in[1];
    float* y = (float*)d_out;

    const size_t slab  = (size_t)B_DIM * O_DIM * sizeof(float);   // 2 MB
    const size_t xT_sz = (size_t)B_DIM * I_DIM * sizeof(float);   // 2 MB
    const size_t wT_sz = (size_t)O_DIM * I_DIM * sizeof(float);   // 4 MB
    const dim3 rgrid(B_DIM * O_DIM / 4 / 256);
    const dim3 tgrid(I_DIM / 32, 512 / 32, 3);
    const dim3 tblk(32, 8);

    if (ws_size >= 16 * slab + xT_sz + wT_sz) {          // 38 MB
        float* part = (float*)d_ws;
        float* xT = part + 16 * (size_t)(B_DIM * O_DIM);
        float* wT = xT + B_DIM * I_DIM;
        transpose3<<<tgrid, tblk, 0, stream>>>(x, xT, W, wT);
        trop_main<I_DIM / 16><<<dim3(O_DIM / OT, B_DIM / BT, 16), 256, 0, stream>>>(xT, wT, part);
        trop_reduce<16><<<rgrid, 256, 0, stream>>>(part, y);
    } else if (ws_size >= 8 * slab + xT_sz + wT_sz) {    // 22 MB
        float* part = (float*)d_ws;
        float* xT = part + 8 * (size_t)(B_DIM * O_DIM);
        float* wT = xT + B_DIM * I_DIM;
        transpose3<<<tgrid, tblk, 0, stream>>>(x, xT, W, wT);
        trop_main<I_DIM / 8><<<dim3(O_DIM / OT, B_DIM / BT, 8), 256, 0, stream>>>(xT, wT, part);
        trop_reduce<8><<<rgrid, 256, 0, stream>>>(part, y);
    } else if (ws_size >= xT_sz + wT_sz) {               // 6 MB: no K-split
        float* xT = (float*)d_ws;
        float* wT = xT + B_DIM * I_DIM;
        transpose3<<<tgrid, tblk, 0, stream>>>(x, xT, W, wT);
        trop_main<I_DIM><<<dim3(O_DIM / OT, B_DIM / BT, 1), 256, 0, stream>>>(xT, wT, y);
    } else {
        trop_naive<<<dim3(B_DIM * O_DIM / 256), 256, 0, stream>>>(x, W, y);
    }
}

// Round 15
// 86.939 us; speedup vs baseline: 4.6104x; 1.0212x over previous
//
#include <hip/hip_runtime.h>
#include <float.h>

// Tropical (max-plus) linear: y[b,o] = max_i (x[b,i] + W[o,i])
// B=512, I=1024, O=1024, fp32. No MFMA (max-plus) -> fp32 VALU.
//
// Round-15 = round-14 (barrier-free wave-private tiles, best: 88.8 us,
// absmax 0) + fp16 K-split slabs (halves 64 MB slab traffic -> 32 MB).
//  * Main K-loop: UNCHANGED from r14 (pinned at ~30 us = 1.45x the 20.4 us
//    serial LDS+VALU floor; invariant under occupancy/barriers/unroll — the
//    residual is issue friction between two saturated pipes; stop tweaking).
//  * Epilogue: acc -> fp16 via scalar cvt+shift+or (epilogue-only), uint2
//    stores. fp16 error ~0.004 << 0.1625 tolerance (r12 measured 0.031 with
//    fp16 compute; here only the OUTPUT is rounded).
//  * Reduce: uint4 loads of fp16 slabs, r13-proven scalar lo16f/hi16f unpack
//    (VGPR 96, zero scratch), fp32 max, fp32 y.
//  CODEGEN RULE (5 demotions r5/r7/r9/r12): pure scalar dataflow in the hot
//  loop; float4/uint4/uint2 only as named immediate load/store temps.

#define B_DIM 512
#define I_DIM 1024
#define O_DIM 1024
#define BT 128           // block b-tile (32 per wave)
#define OT 128           // block o-tile (full, per wave)
#define KT 8             // k per staged chunk

__device__ __forceinline__ void g2lds16(const float* g, float* l) {
    __builtin_amdgcn_global_load_lds(
        (const __attribute__((address_space(1))) void*)g,
        (__attribute__((address_space(3))) void*)l, 16, 0, 0);
}

// scalar fp16 helpers (r13-proven clean codegen)
__device__ __forceinline__ unsigned pack2h(float a, float b) {
    const unsigned lo = (unsigned)__builtin_bit_cast(unsigned short, (_Float16)a);
    const unsigned hi = (unsigned)__builtin_bit_cast(unsigned short, (_Float16)b);
    return lo | (hi << 16);
}
__device__ __forceinline__ float lo16f(unsigned u) {
    return (float)__builtin_bit_cast(_Float16, (unsigned short)(u & 0xffffu));
}
__device__ __forceinline__ float hi16f(unsigned u) {
    return (float)__builtin_bit_cast(_Float16, (unsigned short)(u >> 16));
}

template <int KB>   // k handled per block
__global__ __launch_bounds__(256, 2) void trop_main(
    const float* __restrict__ xT,    // [I_DIM][B_DIM]
    const float* __restrict__ wT,    // [I_DIM][O_DIM]
    _Float16* __restrict__ part)     // [KSPLIT][B_DIM][O_DIM] fp16 slabs
{
    constexpr int NCH = KB / KT;
    static_assert(KB % KT == 0, "");
    __shared__ __align__(16) float xs[4][2][KT * 32];    // [wave][buf][k][b32]
    __shared__ __align__(16) float ws[4][2][KT * 128];   // [wave][buf][k][o]

    const int tid  = threadIdx.x;
    const int wave = tid >> 6;          // 0..3: owns b-rows [32*wave, +32)
    const int lane = tid & 63;
    const int to   = lane & 15;         // o-quad selector (0..15)
    const int tbw  = lane >> 4;         // b-quad selector within wave (0..3)
    const int o0 = blockIdx.x * OT;
    const int b0 = blockIdx.y * BT;
    const int bw0 = b0 + 32 * wave;     // wave's b-slice base
    const int kz = blockIdx.z;
    const int kbase = kz * KB;

    const int rk8 = lane >> 3;          // x DMA: k-row 0..7
    const int xc4 = (lane & 7) * 4;     //        b-col (floats)
    const int rk2 = lane >> 5;          // w DMA: k-subrow 0..1
    const int wc4 = (lane & 31) * 4;    //        o-col (floats)

    float acc[8][8];                    // SCALAR regs — the only clean form
    #pragma unroll
    for (int i = 0; i < 8; ++i)
        #pragma unroll
        for (int j = 0; j < 8; ++j)
            acc[i][j] = -FLT_MAX;

    auto stage = [&](int c, int buf) {
        const int k0 = kbase + c * KT;
        g2lds16(&xT[(size_t)(k0 + rk8) * B_DIM + bw0 + xc4],
                &xs[wave][buf][0]);
        #pragma unroll
        for (int t = 0; t < 4; ++t)
            g2lds16(&wT[(size_t)(k0 + 2 * t + rk2) * O_DIM + o0 + wc4],
                    &ws[wave][buf][t * 256]);
    };

    auto compute = [&](int buf) {
        const float* xB = &xs[wave][buf][4 * tbw];   // static imm offsets
        const float* wB = &ws[wave][buf][4 * to];
        #pragma unroll                                // 4 k-pairs
        for (int k = 0; k < KT; k += 2) {
            const float4 xa0 = *(const float4*)&xB[k * 32];
            const float4 xa1 = *(const float4*)&xB[k * 32 + 16];
            const float4 xb0 = *(const float4*)&xB[(k + 1) * 32];
            const float4 xb1 = *(const float4*)&xB[(k + 1) * 32 + 16];
            const float4 wa0 = *(const float4*)&wB[k * 128];
            const float4 wa1 = *(const float4*)&wB[k * 128 + 64];
            const float4 wb0 = *(const float4*)&wB[(k + 1) * 128];
            const float4 wb1 = *(const float4*)&wB[(k + 1) * 128 + 64];

            const float xa[8] = {xa0.x, xa0.y, xa0.z, xa0.w, xa1.x, xa1.y, xa1.z, xa1.w};
            const float xb[8] = {xb0.x, xb0.y, xb0.z, xb0.w, xb1.x, xb1.y, xb1.z, xb1.w};
            const float wa[8] = {wa0.x, wa0.y, wa0.z, wa0.w, wa1.x, wa1.y, wa1.z, wa1.w};
            const float wb[8] = {wb0.x, wb0.y, wb0.z, wb0.w, wb1.x, wb1.y, wb1.z, wb1.w};

            #pragma unroll
            for (int i = 0; i < 8; ++i)
                #pragma unroll
                for (int j = 0; j < 8; ++j) {
                    const float s0 = xa[i] + wa[j];
                    const float s1 = xb[i] + wb[j];
                    acc[i][j] = fmaxf(acc[i][j], fmaxf(s0, s1));   // v_max3_f32
                }
        }
    };

    // barrier-free pipeline: wave-private buffers, compiler vmcnt only
    stage(0, 0);
    #pragma unroll
    for (int c = 0; c < NCH; ++c) {
        if (c + 1 < NCH) stage(c + 1, (c + 1) & 1);
        compute(c & 1);
    }

    // epilogue: pack to fp16 (scalar cvt+or), uint2 stores into fp16 slab
    _Float16* pout = part + (size_t)kz * (B_DIM * O_DIM);
    #pragma unroll
    for (int i = 0; i < 8; ++i) {
        const int b = bw0 + (i >> 2) * 16 + 4 * tbw + (i & 3);
        const uint2 v0 = make_uint2(pack2h(acc[i][0], acc[i][1]),
                                    pack2h(acc[i][2], acc[i][3]));
        const uint2 v1 = make_uint2(pack2h(acc[i][4], acc[i][5]),
                                    pack2h(acc[i][6], acc[i][7]));
        *(uint2*)((char*)pout + ((size_t)b * O_DIM + o0 + 4 * to) * 2)      = v0;
        *(uint2*)((char*)pout + ((size_t)b * O_DIM + o0 + 64 + 4 * to) * 2) = v1;
    }
}

// ---- fused transpose: z=0 -> xT from x (512x1024); z=1,2 -> wT halves
__global__ __launch_bounds__(256) void transpose3(
    const float* __restrict__ x, float* __restrict__ xT,
    const float* __restrict__ W, float* __restrict__ wT)
{
    __shared__ float tile[32][33];
    const int tx = threadIdx.x;   // 0..31
    const int ty = threadIdx.y;   // 0..7
    const int z  = blockIdx.z;
    const float* in; float* out; int dst_ld;
    if (z == 0) { in = x;                  out = xT;            dst_ld = B_DIM; }
    else        { in = W + (size_t)(z - 1) * 512 * I_DIM;
                  out = wT + (z - 1) * 512;                     dst_ld = O_DIM; }
    const int r0 = blockIdx.y * 32;
    const int c0 = blockIdx.x * 32;
    #pragma unroll
    for (int i = 0; i < 4; ++i)
        tile[ty + 8 * i][tx] = in[(size_t)(r0 + ty + 8 * i) * I_DIM + c0 + tx];
    __syncthreads();
    #pragma unroll
    for (int i = 0; i < 4; ++i)
        out[(size_t)(c0 + ty + 8 * i) * dst_ld + r0 + tx] = tile[tx][ty + 8 * i];
}

// ---- reduce fp16 slabs -> fp32 y. Each thread: 8 consecutive outputs.
template <int KS>
__global__ __launch_bounds__(256) void trop_reduce_h(
    const _Float16* __restrict__ part, float* __restrict__ y)
{
    constexpr size_t N = (size_t)B_DIM * O_DIM;    // halves per slab
    const int idx = blockIdx.x * 256 + threadIdx.x;
    float m0 = -FLT_MAX, m1 = -FLT_MAX, m2 = -FLT_MAX, m3 = -FLT_MAX;
    float m4 = -FLT_MAX, m5 = -FLT_MAX, m6 = -FLT_MAX, m7 = -FLT_MAX;
    #pragma unroll
    for (int s = 0; s < KS; ++s) {
        const uint4 v = *(const uint4*)((const char*)part + (s * N + (size_t)idx * 8) * 2);
        m0 = fmaxf(m0, lo16f(v.x)); m1 = fmaxf(m1, hi16f(v.x));
        m2 = fmaxf(m2, lo16f(v.y)); m3 = fmaxf(m3, hi16f(v.y));
        m4 = fmaxf(m4, lo16f(v.z)); m5 = fmaxf(m5, hi16f(v.z));
        m6 = fmaxf(m6, lo16f(v.w)); m7 = fmaxf(m7, hi16f(v.w));
    }
    const float4 o0 = make_float4(m0, m1, m2, m3);
    const float4 o1 = make_float4(m4, m5, m6, m7);
    ((float4*)y)[2 * idx]     = o0;
    ((float4*)y)[2 * idx + 1] = o1;
}

// correctness-net fallback if d_ws is tiny (fp32, exact)
__global__ __launch_bounds__(256) void trop_naive(
    const float* __restrict__ x, const float* __restrict__ W,
    float* __restrict__ y)
{
    const int idx = blockIdx.x * 256 + threadIdx.x;
    const int b = idx / O_DIM, o = idx % O_DIM;
    float m = -FLT_MAX;
    for (int i = 0; i < I_DIM; ++i)
        m = fmaxf(m, x[b * I_DIM + i] + W[o * I_DIM + i]);
    y[idx] = m;
}

extern "C" void kernel_launch(void* const* d_in, const int* in_sizes, int n_in,
                              void* d_out, int out_size, void* d_ws, size_t ws_size,
                              hipStream_t stream) {
    const float* x = (const float*)d_in[0];
    const float* W = (const float*)d_in[1];
    float* y = (float*)d_out;

    const size_t slab_h = (size_t)B_DIM * O_DIM * 2;              // 1 MB fp16
    const size_t xT_sz  = (size_t)B_DIM * I_DIM * sizeof(float);  // 2 MB
    const size_t wT_sz  = (size_t)O_DIM * I_DIM * sizeof(float);  // 4 MB
    const dim3 rgrid(B_DIM * O_DIM / 8 / 256);                    // 256 blocks
    const dim3 tgrid(I_DIM / 32, 512 / 32, 3);
    const dim3 tblk(32, 8);

    if (ws_size >= 16 * slab_h + xT_sz + wT_sz) {        // 22 MB
        _Float16* part = (_Float16*)d_ws;
        float* xT = (float*)((char*)d_ws + 16 * slab_h);
        float* wT = xT + (size_t)B_DIM * I_DIM;
        transpose3<<<tgrid, tblk, 0, stream>>>(x, xT, W, wT);
        trop_main<I_DIM / 16><<<dim3(O_DIM / OT, B_DIM / BT, 16), 256, 0, stream>>>(xT, wT, part);
        trop_reduce_h<16><<<rgrid, 256, 0, stream>>>(part, y);
    } else if (ws_size >= 8 * slab_h + xT_sz + wT_sz) {  // 14 MB
        _Float16* part = (_Float16*)d_ws;
        float* xT = (float*)((char*)d_ws + 8 * slab_h);
        float* wT = xT + (size_t)B_DIM * I_DIM;
        transpose3<<<tgrid, tblk, 0, stream>>>(x, xT, W, wT);
        trop_main<I_DIM / 8><<<dim3(O_DIM / OT, B_DIM / BT, 8), 256, 0, stream>>>(xT, wT, part);
        trop_reduce_h<8><<<rgrid, 256, 0, stream>>>(part, y);
    } else if (ws_size >= slab_h + xT_sz + wT_sz) {      // 7 MB: no K-split
        _Float16* part = (_Float16*)d_ws;
        float* xT = (float*)((char*)d_ws + slab_h);
        float* wT = xT + (size_t)B_DIM * I_DIM;
        transpose3<<<tgrid, tblk, 0, stream>>>(x, xT, W, wT);
        trop_main<I_DIM><<<dim3(O_DIM / OT, B_DIM / BT, 1), 256, 0, stream>>>(xT, wT, part);
        trop_reduce_h<1><<<rgrid, 256, 0, stream>>>(part, y);
    } else {
        trop_naive<<<dim3(B_DIM * O_DIM / 256), 256, 0, stream>>>(x, W, y);
    }
}